// Round 13
// baseline (524.620 us; speedup 1.0000x reference)
//
#include <hip/hip_runtime.h>
#include <math.h>

#define S      384
#define N0     192
#define NE     191
#define MAXADJ 16
#define E50    1.9287498e-22f   // exp(-50)

// float workspace offsets (round-5 layout)
#define OFF_W     0
#define OFF_WT    36864
#define OFF_PHIE  73728
#define OFF_MSGF  147456
#define OFF_MSGB  221184
#define OFF_MXF   294912
#define OFF_MXB   368640
#define OFF_SBT   442368
#define OFF_BASET 516096
#define OFF_U     589824
#define OFF_V     590016
#define OFF_MAXF  590400
#define OFF_MAXB  590592
#define OFF_HIF   590784
#define OFF_LOF   590976
#define OFF_HIB   591168
#define OFF_LOB   591360
#define OFF_UHI   591552
#define OFF_INT   591616
// int offsets relative to (int*)(ws + OFF_INT)
#define IOFF_DSTF 0
#define IOFF_DSTB 192
#define IOFF_CNTF 384
#define IOFF_CNTB 576
#define IOFF_ADJF 768
#define IOFF_ADJB (768 + 192*MAXADJ)

// ---------------------------------------------------------------------------
__global__ __launch_bounds__(256) void k_setup(
    const int* __restrict__ E1f, const int* __restrict__ E1b,
    const float* __restrict__ cost, const float* __restrict__ constr,
    float* __restrict__ ws)
{
    int tid = blockIdx.x * 256 + threadIdx.x;
    int nt  = gridDim.x * 256;

    for (int idx = tid; idx < 192 * 192; idx += nt) {
        int k = idx / 192, s = idx % 192;
        float w = __expf(-50.f * (1.f - constr[idx]));
        ws[OFF_W + idx] = w;               // W[k][s]  (fwd GEMV weights)
        ws[OFF_WT + s * 192 + k] = w;      // WT[k][s] = W[s][k] (bwd)
    }
    for (int idx = tid; idx < 192 * S; idx += nt) {
        int j = idx / S, i = idx % S;
        ws[OFF_PHIE + idx] = (i < N0) ? -10.f * cost[j * N0 + i] : 0.f;
        ws[OFF_MSGF + idx] = 0.f;
        ws[OFF_MSGB + idx] = 0.f;
        ws[OFF_MXF + idx]  = 0.f;
        ws[OFF_MXB + idx]  = (j < NE) ? 1.f : 0.f;   // exp(0-0)=1
    }
    for (int i = tid; i < S; i += nt) ws[OFF_V + i] = 0.f;
    for (int i = tid; i < 192; i += nt) {
        ws[OFF_U + i] = 0.f;
        ws[OFF_MAXF + i] = 0.f; ws[OFF_MAXB + i] = 0.f;
        ws[OFF_HIF + i] = 0.f;  ws[OFF_LOF + i] = 0.f;
        ws[OFF_HIB + i] = (i < NE) ? 192.f : 0.f;
        ws[OFF_LOB + i] = (i < NE) ? 192.f : 0.f;
    }
    if (tid == 0) ws[OFF_UHI] = 0.f;

    int* ip = (int*)(ws + OFF_INT);
    for (int e = tid; e < 192; e += nt) {
        ip[IOFF_DSTF + e] = (e < NE) ? E1f[2 * e + 1] : 0;
        ip[IOFF_DSTB + e] = (e < NE) ? E1b[2 * e + 1] : 0;
    }
    for (int b = tid; b < 192; b += nt) {
        int cf = 0, cb = 0;
        for (int e = 0; e < NE; ++e) {
            if (E1f[2 * e + 1] == b && cf < MAXADJ) ip[IOFF_ADJF + b * MAXADJ + cf++] = e;
            if (E1b[2 * e + 1] == b && cb < MAXADJ) ip[IOFF_ADJB + b * MAXADJ + cb++] = e;
        }
        ip[IOFF_CNTF + b] = cf;
        ip[IOFF_CNTB + b] = cb;
    }
}

// ---------------------------------------------------------------------------
// K1 (merged A+B): ONE block, 1024 threads (16 waves).
//  part1: wave w owns rows j = 12w..12w+11: gather SFT/SBT from msgs,
//         BASET[j] = phie_neg + sft + sbt, store SBT, u[j] = LSE_i(BT - Vprev).
//  uhi = LSE_i(-Vprev).
//  part3: v[i] = log( sum_{j<192} exp(BT[j][i]-u[j]) + 192*exp(-uhi) ),
//         768 threads = 384 cols x 2 j-halves, online LSE + pair merge.
__global__ __launch_bounds__(1024) void k_ab(float* __restrict__ ws)
{
    __shared__ float uS[192];
    __shared__ float vP[384];
    __shared__ float pm[768], pssum[768];
    __shared__ float uhiS;

    int t = threadIdx.x;
    int l = t & 63, w = t >> 6;          // wave 0..15
    const int* ip = (const int*)(ws + OFF_INT);

    if (t < 384) vP[t] = ws[OFF_V + t];  // cache V_prev before overwrite
    __syncthreads();

    // ---- part 1: gather + BASET/SBT + u ----
    for (int r = 0; r < 12; ++r) {
        int j = w * 12 + r;
        int cF = ip[IOFF_CNTF + j], cB = ip[IOFF_CNTB + j];
        const int* aF = ip + IOFF_ADJF + j * MAXADJ;
        const int* aB = ip + IOFF_ADJB + j * MAXADJ;

        float sft[6] = {0,0,0,0,0,0}, sbt[6] = {0,0,0,0,0,0};
        for (int q = 0; q < cF; ++q) {
            const float* mr = ws + OFF_MSGF + aF[q] * S;
#pragma unroll
            for (int p = 0; p < 6; ++p) sft[p] += mr[l + 64 * p];
        }
        for (int q = 0; q < cB; ++q) {
            const float* mr = ws + OFF_MSGB + aB[q] * S;
#pragma unroll
            for (int p = 0; p < 6; ++p) sbt[p] += mr[l + 64 * p];
        }

        float x[6], m = -1e30f;
#pragma unroll
        for (int p = 0; p < 6; ++p) {
            int i = l + 64 * p;
            float bt = ws[OFF_PHIE + j * S + i] + sft[p] + sbt[p];
            ws[OFF_BASET + j * S + i] = bt;
            ws[OFF_SBT + j * S + i]   = sbt[p];
            x[p] = bt - vP[i];
            m = fmaxf(m, x[p]);
        }
#pragma unroll
        for (int o = 32; o; o >>= 1) m = fmaxf(m, __shfl_xor(m, o, 64));
        float sm = 0.f;
#pragma unroll
        for (int p = 0; p < 6; ++p) sm += __expf(x[p] - m);
#pragma unroll
        for (int o = 32; o; o >>= 1) sm += __shfl_xor(sm, o, 64);
        if (l == 0) {
            float uj = m + __logf(sm);
            ws[OFF_U + j] = uj;
            uS[j] = uj;
        }
    }

    // ---- uhi (wave 0) ----
    if (w == 0) {
        float x[6], m = -1e30f;
#pragma unroll
        for (int q = 0; q < 6; ++q) { x[q] = -vP[l + 64 * q]; m = fmaxf(m, x[q]); }
#pragma unroll
        for (int o = 32; o; o >>= 1) m = fmaxf(m, __shfl_xor(m, o, 64));
        float sm = 0.f;
#pragma unroll
        for (int q = 0; q < 6; ++q) sm += __expf(x[q] - m);
#pragma unroll
        for (int o = 32; o; o >>= 1) sm += __shfl_xor(sm, o, 64);
        if (l == 0) {
            float uh = m + __logf(sm);
            uhiS = uh;
            ws[OFF_UHI] = uh;
        }
    }
    __threadfence_block();
    __syncthreads();

    // ---- part 3: v ----
    if (t < 768) {
        int half = t / 384, i = t - half * 384;
        float m = -1e30f, sm = 0.f;
        int j0 = half * 96;
#pragma unroll 4
        for (int j = j0; j < j0 + 96; ++j) {
            float x = ws[OFF_BASET + j * S + i] - uS[j];
            float mn = fmaxf(m, x);
            sm = sm * __expf(m - mn) + __expf(x - mn);
            m = mn;
        }
        pm[half * 384 + i] = m;
        pssum[half * 384 + i] = sm;
    }
    __syncthreads();
    if (t < 384) {
        float M = pm[t], Ss = pssum[t];
        float m2 = pm[384 + t], s2 = pssum[384 + t];
        float mn = fmaxf(M, m2);
        Ss = Ss * __expf(M - mn) + s2 * __expf(m2 - mn);
        M = mn;
        float xt = __logf(192.f) - uhiS;
        mn = fmaxf(M, xt);
        Ss = Ss * __expf(M - mn) + __expf(xt - mn);
        ws[OFF_V + t] = mn + __logf(Ss);
    }
}

// ---------------------------------------------------------------------------
// K2/K3: msg update with fused GEMV + colsum. One block per edge. (round-5)
__global__ __launch_bounds__(256) void k_msg(float* __restrict__ ws, int fwd)
{
    __shared__ float mx[192];
    __shared__ float red[256], red2[256];
    int e = blockIdx.x, t = threadIdx.x;
    const int* ip = (const int*)(ws + OFF_INT);

    float* MSG  = ws + (fwd ? OFF_MSGF : OFF_MSGB);
    float* MX   = ws + (fwd ? OFF_MXF  : OFF_MXB);
    const float* MXin = ws + (fwd ? OFF_MXB : OFF_MXF);
    const float* Wm   = ws + (fwd ? OFF_W   : OFF_WT);

    float mPrev = fwd ? ws[OFF_MAXB + e] : ws[OFF_MAXF + e];
    float hi    = fwd ? ws[OFF_HIB + e]  : ws[OFF_HIF + e];
    float lo    = fwd ? ws[OFF_LOB + e]  : ws[OFF_LOF + e];
    float addLo = fwd ? hi : E50 * hi;
    float yHi   = fwd ? (hi + E50 * lo) : (lo + hi);
    float lyHi  = __logf(yHi);

    int d = fwd ? ip[IOFF_DSTF + e] : ip[IOFF_DSTB + e];
    float uD = ws[OFF_U + d];
    const float* V = ws + OFF_V;

    if (t < 192) mx[t] = MXin[e * S + t];
    __syncthreads();

    // GEMV: y = sum_k Wm[k][s] * mx[k], thread t owns s=t (t<192)
    float acc = 0.f;
    if (t < 192) {
#pragma unroll 8
        for (int k = 0; k < 192; ++k)
            acc += Wm[k * 192 + t] * mx[k];
    }

    int s1 = t, s2 = t + 256;
    float bt1, bt2 = 0.f;
    if (fwd) {
        bt1 = ws[OFF_BASET + d * S + s1];
        if (s2 < S) bt2 = ws[OFF_BASET + d * S + s2];
    } else {
        int cF = ip[IOFF_CNTF + d];
        const int* aF = ip + IOFF_ADJF + d * MAXADJ;
        bt1 = ws[OFF_PHIE + d * S + s1] + ws[OFF_SBT + d * S + s1];
        if (s2 < S) bt2 = ws[OFF_PHIE + d * S + s2] + ws[OFF_SBT + d * S + s2];
        for (int q = 0; q < cF; ++q) {
            const float* mr = ws + OFF_MSGF + aF[q] * S;
            bt1 += mr[s1];
            if (s2 < S) bt2 += mr[s2];
        }
    }

    float logy1 = (s1 < 192) ? __logf(acc + addLo) : lyHi;
    float x1 = 0.5f * (MSG[e * S + s1] + uD + V[s1] - bt1 + mPrev + logy1);
    float x2 = 1e30f;
    if (s2 < S) {
        x2 = 0.5f * (MSG[e * S + s2] + uD + V[s2] - bt2 + mPrev + lyHi);
        MSG[e * S + s2] = x2;
    }
    MSG[e * S + s1] = x1;

    red[t] = fminf(x1, x2);
    __syncthreads();
    for (int o = 128; o; o >>= 1) {
        if (t < o) red[t] = fminf(red[t], red[t + o]);
        __syncthreads();
    }
    float mn = red[0];
    __syncthreads();

    float mx1 = __expf(mn - x1);
    float mx2 = (s2 < S) ? __expf(mn - x2) : 0.f;
    MX[e * S + s1] = mx1;
    if (s2 < S) MX[e * S + s2] = mx2;
    if (t == 0) {
        if (fwd) ws[OFF_MAXF + e] = -mn; else ws[OFF_MAXB + e] = -mn;
    }

    red[t]  = (t < 192) ? mx1 : 0.f;
    red2[t] = ((t >= 192) ? mx1 : 0.f) + mx2;
    __syncthreads();
    for (int o = 128; o; o >>= 1) {
        if (t < o) { red[t] += red[t + o]; red2[t] += red2[t + o]; }
        __syncthreads();
    }
    if (t == 0) {
        if (fwd) { ws[OFF_LOF + e] = red[0]; ws[OFF_HIF + e] = red2[0]; }
        else     { ws[OFF_LOB + e] = red[0]; ws[OFF_HIB + e] = red2[0]; }
    }
}

// final: out[a][b] = exp(min(btFinal[a][b] - U[a] - V[b], 0))
__global__ __launch_bounds__(256) void k_final(const float* __restrict__ ws,
                                               float* __restrict__ out)
{
    int t = threadIdx.x;
    const int* ip = (const int*)(ws + OFF_INT);
    const float* V = ws + OFF_V;
    float uhi = ws[OFF_UHI];

    for (int a = blockIdx.x * 6; a < blockIdx.x * 6 + 6; ++a) {
        if (a < 192) {
            float ua = ws[OFF_U + a];
            int cF = ip[IOFF_CNTF + a], cB = ip[IOFF_CNTB + a];
            const int* aF = ip + IOFF_ADJF + a * MAXADJ;
            const int* aB = ip + IOFF_ADJB + a * MAXADJ;
            for (int b = t; b < S; b += 256) {
                float bt = ws[OFF_PHIE + a * S + b];
                for (int q = 0; q < cF; ++q) bt += ws[OFF_MSGF + aF[q] * S + b];
                for (int q = 0; q < cB; ++q) bt += ws[OFF_MSGB + aB[q] * S + b];
                out[a * S + b] = __expf(fminf(bt - ua - V[b], 0.f));
            }
        } else {
            for (int b = t; b < S; b += 256)
                out[a * S + b] = __expf(fminf(-uhi - V[b], 0.f));
        }
    }
}

// ---------------------------------------------------------------------------
extern "C" void kernel_launch(void* const* d_in, const int* in_sizes, int n_in,
                              void* d_out, int out_size, void* d_ws, size_t ws_size,
                              hipStream_t stream)
{
    const int*   E1f    = (const int*)d_in[0];
    const int*   E1b    = (const int*)d_in[1];
    const float* cost   = (const float*)d_in[3];
    const float* constr = (const float*)d_in[4];

    float* ws = (float*)d_ws;

    k_setup<<<64, 256, 0, stream>>>(E1f, E1b, cost, constr, ws);

    for (int step = 0; step < 8; ++step) {
        k_ab<<<1, 1024, 0, stream>>>(ws);
        k_msg<<<NE, 256, 0, stream>>>(ws, 1);
        k_msg<<<NE, 256, 0, stream>>>(ws, 0);
    }

    k_final<<<64, 256, 0, stream>>>(ws, (float*)d_out);
}